// Round 13
// baseline (149.140 us; speedup 1.0000x reference)
//
#include <hip/hip_runtime.h>
#include <hip/hip_bf16.h>

typedef __bf16 bf16;
typedef bf16 bf16x8 __attribute__((ext_vector_type(8)));
typedef bf16 bf16x4 __attribute__((ext_vector_type(4)));
typedef float f32x4 __attribute__((ext_vector_type(4)));

#define B_  2
#define S_  2048
#define D_  1024
#define H_  16
#define HD_ 64
#define M_  4096   // B_*S_
#define K_  1024
#define N_  1024

#if __has_builtin(__builtin_amdgcn_exp2f)
#define EXP2F(x) __builtin_amdgcn_exp2f(x)
#else
#define EXP2F(x) exp2f(x)
#endif

__device__ __forceinline__ void gld16(const bf16* g, bf16* l) {
    __builtin_amdgcn_global_load_lds(
        (const __attribute__((address_space(1))) unsigned int*)(g),
        (__attribute__((address_space(3))) unsigned int*)(l), 16, 0, 0);
}

// ---------------- pack_x: X fp32 -> bf16 [3][M][K] ---------------------------
__global__ void pack_x(const float* __restrict__ xq, const float* __restrict__ xk,
                       const float* __restrict__ xv, bf16* __restrict__ out) {
    int t = blockIdx.y;
    const float* src = (t == 0) ? xq : (t == 1) ? xk : xv;
    bf16* dst = out + (size_t)t * M_ * K_;
    int idx = (blockIdx.x * 256 + threadIdx.x) * 4;
    float4 v = *(const float4*)&src[idx];
    bf16x4 o = { (bf16)v.x, (bf16)v.y, (bf16)v.z, (bf16)v.w };
    *(bf16x4*)&dst[idx] = o;
}

// ---------------- pack_w: weights fp32 -> bf16 transposed --------------------
__global__ void pack_w(const float* __restrict__ wq, const float* __restrict__ wk,
                       const float* __restrict__ wv, const float* __restrict__ wo,
                       bf16* __restrict__ out) {
    int t = blockIdx.y;
    bf16* dst = out + (size_t)t * N_ * K_;
    int o = blockIdx.x * 256 + threadIdx.x;
    int n = o >> 10, k = o & 1023;
    if (t == 3) {
        dst[o] = (bf16)wo[k * D_ + n];
    } else {
        const float* src = (t == 0) ? wq : (t == 1) ? wk : wv;
        dst[o] = (bf16)src[(n >> 6) * (D_ * HD_) + k * HD_ + (n & 63)];
    }
}

// ---------------- QKV projection GEMM: all-bf16, dual source/read swizzle ----
// Both operands staged async via global_load_lds (linear dest, inverse-swizzled
// global source); fragment reads XOR-swizzled -> 2-way max bank aliasing.
// 2-phase dbuf, branch-free hot loop.
__global__ __launch_bounds__(256) void gemm_qkv(
        const bf16* __restrict__ X, const bf16* __restrict__ Wt,
        const float* __restrict__ bq, const float* __restrict__ bk,
        const float* __restrict__ bv, bf16* __restrict__ QKV) {
    __shared__ __align__(16) bf16 As[2][128 * 32];
    __shared__ __align__(16) bf16 Bs[2][128 * 32];
    int t = blockIdx.z;
    const bf16* A = X + (size_t)t * M_ * K_;
    const bf16* W = Wt + (size_t)t * N_ * K_;
    const float* bias = (t == 0) ? bq : (t == 1) ? bk : bv;
    int m0 = blockIdx.x * 128, n0 = blockIdx.y * 128;
    int tid = threadIdx.x;
    int w = tid >> 6, l = tid & 63, lr = l & 15, lg = l >> 4;
    int wr = (w >> 1) * 64, wc = (w & 1) * 64;
    int srow = l >> 2;
    int sscol = ((l & 3) ^ ((srow >> 1) & 3)) * 8;   // inverse-swizzled source
    int aoff[4], boff[4];
    #pragma unroll
    for (int i = 0; i < 4; i++) {
        int ra = wr + i * 16 + lr, rb = wc + i * 16 + lr;
        aoff[i] = ra * 64 + ((lg ^ ((ra >> 1) & 3)) * 16);   // bytes
        boff[i] = rb * 64 + ((lg ^ ((rb >> 1) & 3)) * 16);
    }
    f32x4 acc[4][4] = {};
    #pragma unroll
    for (int c = 0; c < 2; c++) {
        int chunk = w * 2 + c;
        gld16(&A[(size_t)(m0 + chunk * 16 + srow) * K_ + sscol], &As[0][chunk * 512]);
        gld16(&W[(size_t)(n0 + chunk * 16 + srow) * K_ + sscol], &Bs[0][chunk * 512]);
    }
    __syncthreads();

    auto do_step = [&](int cb) {
        bf16x8 af[4], bfr[4];
        #pragma unroll
        for (int mi = 0; mi < 4; mi++) af[mi] = *(const bf16x8*)((const char*)As[cb] + aoff[mi]);
        #pragma unroll
        for (int ni = 0; ni < 4; ni++) bfr[ni] = *(const bf16x8*)((const char*)Bs[cb] + boff[ni]);
        #pragma unroll
        for (int mi = 0; mi < 4; mi++)
            #pragma unroll
            for (int ni = 0; ni < 4; ni++)
                acc[mi][ni] = __builtin_amdgcn_mfma_f32_16x16x32_bf16(af[mi], bfr[ni], acc[mi][ni], 0, 0, 0);
    };

    int cur = 0;
    for (int k0 = 0; k0 < K_ - 32; k0 += 32) {
        int nxt = cur ^ 1;
        #pragma unroll
        for (int c = 0; c < 2; c++) {
            int chunk = w * 2 + c;
            gld16(&A[(size_t)(m0 + chunk * 16 + srow) * K_ + k0 + 32 + sscol], &As[nxt][chunk * 512]);
            gld16(&W[(size_t)(n0 + chunk * 16 + srow) * K_ + k0 + 32 + sscol], &Bs[nxt][chunk * 512]);
        }
        do_step(cur);
        __syncthreads();
        cur = nxt;
    }
    do_step(cur);

    // Q: fold 1/sqrt(HD) AND log2(e) so attention can use exp2 directly
    float qscale = (t == 0) ? 0.125f * 1.4426950408889634f : 1.0f;
    #pragma unroll
    for (int mi = 0; mi < 4; mi++)
        #pragma unroll
        for (int ni = 0; ni < 4; ni++)
            #pragma unroll
            for (int i = 0; i < 4; i++) {
                int m = m0 + wr + mi * 16 + lg * 4 + i;
                int n = n0 + wc + ni * 16 + lr;
                float v = (acc[mi][ni][i] + bias[n]) * qscale;
                int b = m >> 11, s = m & 2047, h = n >> 6, hd = n & 63;
                QKV[((((size_t)t * B_ + b) * H_ + h) * S_ + s) * HD_ + hd] = (bf16)v;
            }
}

// ---------------- output projection GEMM (same structure, fp32 out) ---------
__global__ __launch_bounds__(256) void gemm_out(
        const bf16* __restrict__ A, const bf16* __restrict__ Wt,
        const float* __restrict__ bo, float* __restrict__ out) {
    __shared__ __align__(16) bf16 As[2][128 * 32];
    __shared__ __align__(16) bf16 Bs[2][128 * 32];
    int m0 = blockIdx.x * 128, n0 = blockIdx.y * 128;
    int tid = threadIdx.x;
    int w = tid >> 6, l = tid & 63, lr = l & 15, lg = l >> 4;
    int wr = (w >> 1) * 64, wc = (w & 1) * 64;
    int srow = l >> 2;
    int sscol = ((l & 3) ^ ((srow >> 1) & 3)) * 8;
    int aoff[4], boff[4];
    #pragma unroll
    for (int i = 0; i < 4; i++) {
        int ra = wr + i * 16 + lr, rb = wc + i * 16 + lr;
        aoff[i] = ra * 64 + ((lg ^ ((ra >> 1) & 3)) * 16);
        boff[i] = rb * 64 + ((lg ^ ((rb >> 1) & 3)) * 16);
    }
    f32x4 acc[4][4] = {};
    #pragma unroll
    for (int c = 0; c < 2; c++) {
        int chunk = w * 2 + c;
        gld16(&A[(size_t)(m0 + chunk * 16 + srow) * K_ + sscol], &As[0][chunk * 512]);
        gld16(&Wt[(size_t)(n0 + chunk * 16 + srow) * K_ + sscol], &Bs[0][chunk * 512]);
    }
    __syncthreads();

    auto do_step = [&](int cb) {
        bf16x8 af[4], bfr[4];
        #pragma unroll
        for (int mi = 0; mi < 4; mi++) af[mi] = *(const bf16x8*)((const char*)As[cb] + aoff[mi]);
        #pragma unroll
        for (int ni = 0; ni < 4; ni++) bfr[ni] = *(const bf16x8*)((const char*)Bs[cb] + boff[ni]);
        #pragma unroll
        for (int mi = 0; mi < 4; mi++)
            #pragma unroll
            for (int ni = 0; ni < 4; ni++)
                acc[mi][ni] = __builtin_amdgcn_mfma_f32_16x16x32_bf16(af[mi], bfr[ni], acc[mi][ni], 0, 0, 0);
    };

    int cur = 0;
    for (int k0 = 0; k0 < K_ - 32; k0 += 32) {
        int nxt = cur ^ 1;
        #pragma unroll
        for (int c = 0; c < 2; c++) {
            int chunk = w * 2 + c;
            gld16(&A[(size_t)(m0 + chunk * 16 + srow) * K_ + k0 + 32 + sscol], &As[nxt][chunk * 512]);
            gld16(&Wt[(size_t)(n0 + chunk * 16 + srow) * K_ + k0 + 32 + sscol], &Bs[nxt][chunk * 512]);
        }
        do_step(cur);
        __syncthreads();
        cur = nxt;
    }
    do_step(cur);

    #pragma unroll
    for (int mi = 0; mi < 4; mi++)
        #pragma unroll
        for (int ni = 0; ni < 4; ni++)
            #pragma unroll
            for (int i = 0; i < 4; i++) {
                int m = m0 + wr + mi * 16 + lg * 4 + i;
                int n = n0 + wc + ni * 16 + lr;
                out[(size_t)m * N_ + n] = acc[mi][ni][i] + bo[n];
            }
}

// ---------------- V transpose: V[bh][s][hd] -> VT[bh][hd][s] ------------------
__global__ __launch_bounds__(256) void transpose_v(const bf16* __restrict__ V,
                                                   bf16* __restrict__ VT) {
    __shared__ __align__(16) bf16 Ls[64][64];
    int s0 = blockIdx.x * 64, bh = blockIdx.y;
    const bf16* src = V + (size_t)bh * S_ * HD_;
    bf16* dst = VT + (size_t)bh * HD_ * S_;
    int tid = threadIdx.x;
    #pragma unroll
    for (int c = tid; c < 512; c += 256) {
        int row = c >> 3, cg = (c & 7) * 8;
        int cgp = cg ^ (((row >> 3) & 3) << 4);          // XOR-swizzle banks
        *(bf16x8*)&Ls[row][cgp] = *(const bf16x8*)&src[(size_t)(s0 + row) * 64 + cg];
    }
    __syncthreads();
    #pragma unroll
    for (int c = tid; c < 512; c += 256) {
        int hd = c >> 3, sg = (c & 7) * 8;
        bf16x8 v;
        #pragma unroll
        for (int e = 0; e < 8; e++) {
            int row = sg + e;
            v[e] = Ls[row][hd ^ (((row >> 3) & 3) << 4)];
        }
        *(bf16x8*)&dst[(size_t)hd * S_ + s0 + sg] = v;
    }
}

// ---------------- causal flash attention (round-5 proven structure) ----------
__global__ __launch_bounds__(512) void attn(const bf16* __restrict__ QKV,
                                            const bf16* __restrict__ VT,
                                            bf16* __restrict__ AO) {
    __shared__ __align__(16) bf16 Ks[2][64][72];
    __shared__ __align__(16) bf16 Vts[2][64][72];   // [hd][kv]
    __shared__ __align__(16) bf16 Ps[8][16][72];
    int bh = blockIdx.y;
    int qt = (bh & 16) ? blockIdx.x : (15 - blockIdx.x);  // balance causal work
    int q0 = qt * 128;
    const bf16* Qp = QKV + (size_t)bh * S_ * HD_;
    const bf16* Kp = QKV + (size_t)(32 + bh) * S_ * HD_;
    const bf16* VTp = VT + (size_t)bh * HD_ * S_;
    int tid = threadIdx.x, w = tid >> 6, l = tid & 63, lr = l & 15, lg = l >> 4;
    int srow = tid >> 3, scg = (tid & 7) * 8;   // staging slot (512 threads)

    bf16x8 aq[2];
    #pragma unroll
    for (int ks = 0; ks < 2; ks++)
        aq[ks] = *(const bf16x8*)&Qp[(size_t)(q0 + w * 16 + lr) * 64 + ks * 32 + lg * 8];

    f32x4 o[4] = {};
    float lsum[4] = {};
    int jmax = 2 * qt + 1;

    *(bf16x8*)&Ks[0][srow][scg]  = *(const bf16x8*)&Kp[(size_t)srow * 64 + scg];
    *(bf16x8*)&Vts[0][srow][scg] = *(const bf16x8*)&VTp[(size_t)srow * S_ + scg];
    __syncthreads();

    for (int j = 0; j <= jmax; ++j) {
        int cur = j & 1;
        bool pf = (j < jmax);
        bf16x8 kreg, vreg;
        if (pf) {
            kreg = *(const bf16x8*)&Kp[(size_t)((j + 1) * 64 + srow) * 64 + scg];
            vreg = *(const bf16x8*)&VTp[(size_t)srow * S_ + (j + 1) * 64 + scg];
        }

        f32x4 sc[4] = {};
        __builtin_amdgcn_s_setprio(1);
        #pragma unroll
        for (int ks = 0; ks < 2; ks++)
            #pragma unroll
            for (int ni = 0; ni < 4; ni++) {
                bf16x8 bk_ = *(const bf16x8*)&Ks[cur][ni * 16 + lr][ks * 32 + lg * 8];
                sc[ni] = __builtin_amdgcn_mfma_f32_16x16x32_bf16(aq[ks], bk_, sc[ni], 0, 0, 0);
            }
        __builtin_amdgcn_s_setprio(0);

        bool diag = (j >= 2 * qt);
        int qrow = w * 16 + lg * 4;
        int kvb = j * 64 - q0;
        #pragma unroll
        for (int ni = 0; ni < 4; ni++)
            #pragma unroll
            for (int i = 0; i < 4; i++) {
                float s = sc[ni][i];
                if (diag && (kvb + ni * 16 + lr > qrow + i)) s = -30000.0f;
                float p = EXP2F(s);
                lsum[i] += p;
                Ps[w][lg * 4 + i][ni * 16 + lr] = (bf16)p;
            }

        __builtin_amdgcn_s_setprio(1);
        #pragma unroll
        for (int ks = 0; ks < 2; ks++) {
            bf16x8 ap = *(const bf16x8*)&Ps[w][lr][ks * 32 + lg * 8];
            #pragma unroll
            for (int nf = 0; nf < 4; nf++) {
                bf16x8 bv_ = *(const bf16x8*)&Vts[cur][nf * 16 + lr][ks * 32 + lg * 8];
                o[nf] = __builtin_amdgcn_mfma_f32_16x16x32_bf16(ap, bv_, o[nf], 0, 0, 0);
            }
        }
        __builtin_amdgcn_s_setprio(0);

        if (pf) {
            *(bf16x8*)&Ks[cur ^ 1][srow][scg]  = kreg;
            *(bf16x8*)&Vts[cur ^ 1][srow][scg] = vreg;
        }
        __syncthreads();
    }

    #pragma unroll
    for (int i = 0; i < 4; i++) {
        #pragma unroll
        for (int xm = 1; xm < 16; xm <<= 1) lsum[i] += __shfl_xor(lsum[i], xm);
    }

    int b = bh >> 4, h = bh & 15;
    #pragma unroll
    for (int i = 0; i < 4; i++) {
        float inv = 1.0f / lsum[i];
        #pragma unroll
        for (int nf = 0; nf < 4; nf++) {
            int m = b * S_ + q0 + w * 16 + lg * 4 + i;
            int d = h * 64 + nf * 16 + lr;
            AO[(size_t)m * D_ + d] = (bf16)(o[nf][i] * inv);
        }
    }
}

// ---------------- launcher ----------------------------------------------------
extern "C" void kernel_launch(void* const* d_in, const int* in_sizes, int n_in,
                              void* d_out, int out_size, void* d_ws, size_t ws_size,
                              hipStream_t stream) {
    const float* xq = (const float*)d_in[0];
    const float* xk = (const float*)d_in[1];
    const float* xv = (const float*)d_in[2];
    const float* wq = (const float*)d_in[4];
    const float* bq = (const float*)d_in[5];
    const float* wk = (const float*)d_in[6];
    const float* bk = (const float*)d_in[7];
    const float* wv = (const float*)d_in[8];
    const float* bv = (const float*)d_in[9];
    const float* wo = (const float*)d_in[10];
    const float* bo = (const float*)d_in[11];
    float* out = (float*)d_out;

    bf16* Xb  = (bf16*)d_ws;                  // [3][M][K] (dead after gemm_qkv)
    bf16* Wb  = Xb  + (size_t)3 * M_ * K_;    // [4][N][K]  (q,k,v,o weights ^T)
    bf16* WoT = Wb  + (size_t)3 * N_ * K_;
    bf16* QKV = WoT + (size_t)N_ * K_;        // [3][B*H][S][HD]
    bf16* AO  = QKV + (size_t)3 * M_ * K_;    // [M][D]
    bf16* VT  = Xb;                           // [B*H][HD][S] aliases dead Xb

    pack_x <<<dim3(M_ * K_ / 1024, 3), 256, 0, stream>>>(xq, xk, xv, Xb);
    pack_w <<<dim3(N_ * K_ / 256, 4), 256, 0, stream>>>(wq, wk, wv, wo, Wb);
    gemm_qkv<<<dim3(M_ / 128, N_ / 128, 3), 256, 0, stream>>>(Xb, Wb, bq, bk, bv, QKV);
    transpose_v<<<dim3(S_ / 64, B_ * H_), 256, 0, stream>>>(QKV + (size_t)2 * M_ * K_, VT);
    attn    <<<dim3(S_ / 128, B_ * H_), 512, 0, stream>>>(QKV, VT, AO);
    gemm_out<<<dim3(M_ / 128, N_ / 128), 256, 0, stream>>>(AO, WoT, bo, out);
}

// Round 14
// 126.924 us; speedup vs baseline: 1.1750x; 1.1750x over previous
//
#include <hip/hip_runtime.h>
#include <hip/hip_bf16.h>

typedef __bf16 bf16;
typedef bf16 bf16x8 __attribute__((ext_vector_type(8)));
typedef bf16 bf16x4 __attribute__((ext_vector_type(4)));
typedef float f32x4 __attribute__((ext_vector_type(4)));

#define B_  2
#define S_  2048
#define D_  1024
#define H_  16
#define HD_ 64
#define M_  4096   // B_*S_
#define K_  1024
#define N_  1024

#if __has_builtin(__builtin_amdgcn_exp2f)
#define EXP2F(x) __builtin_amdgcn_exp2f(x)
#else
#define EXP2F(x) exp2f(x)
#endif

__device__ __forceinline__ void gld16(const bf16* g, bf16* l) {
    __builtin_amdgcn_global_load_lds(
        (const __attribute__((address_space(1))) unsigned int*)(g),
        (__attribute__((address_space(3))) unsigned int*)(l), 16, 0, 0);
}
__device__ __forceinline__ void gld16f(const float* g, float* l) {
    __builtin_amdgcn_global_load_lds(
        (const __attribute__((address_space(1))) unsigned int*)(g),
        (__attribute__((address_space(3))) unsigned int*)(l), 16, 0, 0);
}

// ---------------- pack: weights fp32 -> bf16 transposed ----------------------
// W[H,D,HD] fp32 -> Wb[t][n=h*64+hd][k=d] bf16 ; t==3 slice does Wo[D,D]->WoT
__global__ void pack_w(const float* __restrict__ wq, const float* __restrict__ wk,
                       const float* __restrict__ wv, const float* __restrict__ wo,
                       bf16* __restrict__ out) {
    int t = blockIdx.y;
    bf16* dst = out + (size_t)t * N_ * K_;
    int o = blockIdx.x * 256 + threadIdx.x;
    int n = o >> 10, k = o & 1023;
    if (t == 3) {
        dst[o] = (bf16)wo[k * D_ + n];
    } else {
        const float* src = (t == 0) ? wq : (t == 1) ? wk : wv;
        dst[o] = (bf16)src[(n >> 6) * (D_ * HD_) + k * HD_ + (n & 63)];
    }
}

// ---------------- QKV projection GEMM: fp32 A staged direct-to-LDS ----------
// A (activations) staged fp32 via global_load_lds: linear LDS dest, per-lane
// INVERSE-swizzled global source; XOR-swizzle applied on read, cvt to bf16 at
// fragment load. B (weights) bf16 LINEAR (r13 lesson: source-permuted staging
// for B defeats request coalescing and loses more than conflicts cost).
__global__ __launch_bounds__(256) void gemm_qkv(
        const float* __restrict__ xq, const float* __restrict__ xk,
        const float* __restrict__ xv, const bf16* __restrict__ Wt,
        const float* __restrict__ bq, const float* __restrict__ bk,
        const float* __restrict__ bv, bf16* __restrict__ QKV) {
    __shared__ __align__(16) float Af[2][128 * 32];
    __shared__ __align__(16) bf16 Bs[2][128 * 32];
    int t = blockIdx.z;
    const float* A = (t == 0) ? xq : (t == 1) ? xk : xv;
    const bf16* W = Wt + (size_t)t * N_ * K_;
    const float* bias = (t == 0) ? bq : (t == 1) ? bk : bv;
    int m0 = blockIdx.x * 128, n0 = blockIdx.y * 128;
    int tid = threadIdx.x;
    int w = tid >> 6, l = tid & 63, lr = l & 15, lg = l >> 4;
    int wr = (w >> 1) * 64, wc = (w & 1) * 64;
    int srow = (l >> 2), scol = (l & 3) * 8;   // B staging slot in a 1KB chunk
    // A staging: tile = 128 rows x 8 slots(16B); wave w covers chunks
    // [w*256, w*256+256) via 4 gld16f; lane l handles chunk base+l.
    // LDS[r][p] = global[r][p ^ (r&7)]  (slots of 4 floats)
    size_t aoff[4];
    #pragma unroll
    for (int c = 0; c < 4; c++) {
        int chunk = w * 256 + c * 64 + l;
        int r = chunk >> 3, p = chunk & 7;
        aoff[c] = (size_t)(m0 + r) * K_ + ((p ^ (r & 7)) << 2);
    }
    f32x4 acc[4][4] = {};
    // prologue: stage k0=0 into buf 0
    #pragma unroll
    for (int c = 0; c < 4; c++)
        gld16f(A + aoff[c], &Af[0][(w * 256 + c * 64) * 4]);
    #pragma unroll
    for (int c = 0; c < 2; c++) {
        int chunk = w * 2 + c;
        gld16(&W[(size_t)(n0 + chunk * 16 + srow) * K_ + scol], &Bs[0][chunk * 512]);
    }
    __syncthreads();
    for (int k0 = 0; k0 < K_; k0 += 32) {
        int cur = (k0 >> 5) & 1, nxt = cur ^ 1;
        if (k0 + 32 < K_) {
            #pragma unroll
            for (int c = 0; c < 4; c++)
                gld16f(A + aoff[c] + k0 + 32, &Af[nxt][(w * 256 + c * 64) * 4]);
            #pragma unroll
            for (int c = 0; c < 2; c++) {
                int chunk = w * 2 + c;
                gld16(&W[(size_t)(n0 + chunk * 16 + srow) * K_ + k0 + 32 + scol], &Bs[nxt][chunk * 512]);
            }
        }
        bf16x8 af[4], bfr[4];
        #pragma unroll
        for (int mi = 0; mi < 4; mi++) {
            int r = wr + mi * 16 + lr;
            f32x4 a0 = *(const f32x4*)((const char*)Af[cur] + r * 128 + (((lg * 2) ^ (r & 7)) * 16));
            f32x4 a1 = *(const f32x4*)((const char*)Af[cur] + r * 128 + (((lg * 2 + 1) ^ (r & 7)) * 16));
            bf16x8 v = { (bf16)a0[0], (bf16)a0[1], (bf16)a0[2], (bf16)a0[3],
                         (bf16)a1[0], (bf16)a1[1], (bf16)a1[2], (bf16)a1[3] };
            af[mi] = v;
        }
        #pragma unroll
        for (int ni = 0; ni < 4; ni++) bfr[ni] = *(const bf16x8*)&Bs[cur][(wc + ni * 16 + lr) * 32 + lg * 8];
        #pragma unroll
        for (int mi = 0; mi < 4; mi++)
            #pragma unroll
            for (int ni = 0; ni < 4; ni++)
                acc[mi][ni] = __builtin_amdgcn_mfma_f32_16x16x32_bf16(af[mi], bfr[ni], acc[mi][ni], 0, 0, 0);
        __syncthreads();   // drains vmcnt (prefetch done) + orders buffer reuse
    }
    // Q: fold 1/sqrt(HD) AND log2(e) so attention can use exp2 directly
    float qscale = (t == 0) ? 0.125f * 1.4426950408889634f : 1.0f;
    #pragma unroll
    for (int mi = 0; mi < 4; mi++)
        #pragma unroll
        for (int ni = 0; ni < 4; ni++)
            #pragma unroll
            for (int i = 0; i < 4; i++) {
                int m = m0 + wr + mi * 16 + lg * 4 + i;
                int n = n0 + wc + ni * 16 + lr;
                float v = (acc[mi][ni][i] + bias[n]) * qscale;
                int b = m >> 11, s = m & 2047, h = n >> 6, hd = n & 63;
                QKV[((((size_t)t * B_ + b) * H_ + h) * S_ + s) * HD_ + hd] = (bf16)v;
            }
}

// ---------------- output projection GEMM (bf16 A, linear, 2-phase) ----------
__global__ __launch_bounds__(256) void gemm_out(
        const bf16* __restrict__ A, const bf16* __restrict__ Wt,
        const float* __restrict__ bo, float* __restrict__ out) {
    __shared__ __align__(16) bf16 As[2][128 * 32];
    __shared__ __align__(16) bf16 Bs[2][128 * 32];
    int m0 = blockIdx.x * 128, n0 = blockIdx.y * 128;
    int tid = threadIdx.x;
    int w = tid >> 6, l = tid & 63, lr = l & 15, lg = l >> 4;
    int wr = (w >> 1) * 64, wc = (w & 1) * 64;
    int srow = (l >> 2), scol = (l & 3) * 8;
    f32x4 acc[4][4] = {};
    #pragma unroll
    for (int c = 0; c < 2; c++) {
        int chunk = w * 2 + c;
        gld16(&A[(size_t)(m0 + chunk * 16 + srow) * K_ + scol], &As[0][chunk * 512]);
        gld16(&Wt[(size_t)(n0 + chunk * 16 + srow) * K_ + scol], &Bs[0][chunk * 512]);
    }
    __syncthreads();
    for (int k0 = 0; k0 < K_; k0 += 32) {
        int cur = (k0 >> 5) & 1, nxt = cur ^ 1;
        if (k0 + 32 < K_) {
            #pragma unroll
            for (int c = 0; c < 2; c++) {
                int chunk = w * 2 + c;
                gld16(&A[(size_t)(m0 + chunk * 16 + srow) * K_ + k0 + 32 + scol], &As[nxt][chunk * 512]);
                gld16(&Wt[(size_t)(n0 + chunk * 16 + srow) * K_ + k0 + 32 + scol], &Bs[nxt][chunk * 512]);
            }
        }
        bf16x8 af[4], bfr[4];
        #pragma unroll
        for (int mi = 0; mi < 4; mi++) af[mi] = *(const bf16x8*)&As[cur][(wr + mi * 16 + lr) * 32 + lg * 8];
        #pragma unroll
        for (int ni = 0; ni < 4; ni++) bfr[ni] = *(const bf16x8*)&Bs[cur][(wc + ni * 16 + lr) * 32 + lg * 8];
        #pragma unroll
        for (int mi = 0; mi < 4; mi++)
            #pragma unroll
            for (int ni = 0; ni < 4; ni++)
                acc[mi][ni] = __builtin_amdgcn_mfma_f32_16x16x32_bf16(af[mi], bfr[ni], acc[mi][ni], 0, 0, 0);
        __syncthreads();
    }
    #pragma unroll
    for (int mi = 0; mi < 4; mi++)
        #pragma unroll
        for (int ni = 0; ni < 4; ni++)
            #pragma unroll
            for (int i = 0; i < 4; i++) {
                int m = m0 + wr + mi * 16 + lg * 4 + i;
                int n = n0 + wc + ni * 16 + lr;
                out[(size_t)m * N_ + n] = acc[mi][ni][i] + bo[n];
            }
}

// ---------------- V transpose: V[bh][s][hd] -> VT[bh][hd][s] ------------------
__global__ __launch_bounds__(256) void transpose_v(const bf16* __restrict__ V,
                                                   bf16* __restrict__ VT) {
    __shared__ __align__(16) bf16 Ls[64][64];
    int s0 = blockIdx.x * 64, bh = blockIdx.y;
    const bf16* src = V + (size_t)bh * S_ * HD_;
    bf16* dst = VT + (size_t)bh * HD_ * S_;
    int tid = threadIdx.x;
    #pragma unroll
    for (int c = tid; c < 512; c += 256) {
        int row = c >> 3, cg = (c & 7) * 8;
        int cgp = cg ^ (((row >> 3) & 3) << 4);          // XOR-swizzle banks
        *(bf16x8*)&Ls[row][cgp] = *(const bf16x8*)&src[(size_t)(s0 + row) * 64 + cg];
    }
    __syncthreads();
    #pragma unroll
    for (int c = tid; c < 512; c += 256) {
        int hd = c >> 3, sg = (c & 7) * 8;
        bf16x8 v;
        #pragma unroll
        for (int e = 0; e < 8; e++) {
            int row = sg + e;
            v[e] = Ls[row][hd ^ (((row >> 3) & 3) << 4)];
        }
        *(bf16x8*)&dst[(size_t)hd * S_ + s0 + sg] = v;
    }
}

// ---------------- causal flash attention (round-5 proven structure) ----------
// Only change vs r11: wave-uniform diag branch — mask cmp/select only runs on
// the ~1-of-17 steps that touch the diagonal.
__global__ __launch_bounds__(512) void attn(const bf16* __restrict__ QKV,
                                            const bf16* __restrict__ VT,
                                            bf16* __restrict__ AO) {
    __shared__ __align__(16) bf16 Ks[2][64][72];
    __shared__ __align__(16) bf16 Vts[2][64][72];   // [hd][kv]
    __shared__ __align__(16) bf16 Ps[8][16][72];
    int bh = blockIdx.y;
    int qt = (bh & 16) ? blockIdx.x : (15 - blockIdx.x);  // CU-pairing: long+short
    int q0 = qt * 128;
    const bf16* Qp = QKV + (size_t)bh * S_ * HD_;
    const bf16* Kp = QKV + (size_t)(32 + bh) * S_ * HD_;
    const bf16* VTp = VT + (size_t)bh * HD_ * S_;
    int tid = threadIdx.x, w = tid >> 6, l = tid & 63, lr = l & 15, lg = l >> 4;
    int srow = tid >> 3, scg = (tid & 7) * 8;   // staging slot (512 threads)

    bf16x8 aq[2];
    #pragma unroll
    for (int ks = 0; ks < 2; ks++)
        aq[ks] = *(const bf16x8*)&Qp[(size_t)(q0 + w * 16 + lr) * 64 + ks * 32 + lg * 8];

    f32x4 o[4] = {};
    float lsum[4] = {};
    int jmax = 2 * qt + 1;

    *(bf16x8*)&Ks[0][srow][scg]  = *(const bf16x8*)&Kp[(size_t)srow * 64 + scg];
    *(bf16x8*)&Vts[0][srow][scg] = *(const bf16x8*)&VTp[(size_t)srow * S_ + scg];
    __syncthreads();

    for (int j = 0; j <= jmax; ++j) {
        int cur = j & 1;
        bool pf = (j < jmax);
        bf16x8 kreg, vreg;
        if (pf) {   // issue next-tile loads NOW; latency hides under compute
            kreg = *(const bf16x8*)&Kp[(size_t)((j + 1) * 64 + srow) * 64 + scg];
            vreg = *(const bf16x8*)&VTp[(size_t)srow * S_ + (j + 1) * 64 + scg];
        }

        f32x4 sc[4] = {};
        __builtin_amdgcn_s_setprio(1);
        #pragma unroll
        for (int ks = 0; ks < 2; ks++)
            #pragma unroll
            for (int ni = 0; ni < 4; ni++) {
                bf16x8 bk_ = *(const bf16x8*)&Ks[cur][ni * 16 + lr][ks * 32 + lg * 8];
                sc[ni] = __builtin_amdgcn_mfma_f32_16x16x32_bf16(aq[ks], bk_, sc[ni], 0, 0, 0);
            }
        __builtin_amdgcn_s_setprio(0);

        int qrow = w * 16 + lg * 4;              // q row (block-local) of elem i=0
        int kvb = j * 64 - q0;                   // kv offset relative to q0
        if (j >= 2 * qt) {                       // wave-uniform: diagonal steps only
            #pragma unroll
            for (int ni = 0; ni < 4; ni++)
                #pragma unroll
                for (int i = 0; i < 4; i++) {
                    float s = sc[ni][i];
                    if (kvb + ni * 16 + lr > qrow + i) s = -30000.0f;
                    float p = EXP2F(s);
                    lsum[i] += p;
                    Ps[w][lg * 4 + i][ni * 16 + lr] = (bf16)p;
                }
        } else {                                 // interior steps: no mask VALU
            #pragma unroll
            for (int ni = 0; ni < 4; ni++)
                #pragma unroll
                for (int i = 0; i < 4; i++) {
                    float p = EXP2F(sc[ni][i]);
                    lsum[i] += p;
                    Ps[w][lg * 4 + i][ni * 16 + lr] = (bf16)p;
                }
        }

        __builtin_amdgcn_s_setprio(1);
        #pragma unroll
        for (int ks = 0; ks < 2; ks++) {
            bf16x8 ap = *(const bf16x8*)&Ps[w][lr][ks * 32 + lg * 8];
            #pragma unroll
            for (int nf = 0; nf < 4; nf++) {
                bf16x8 bv_ = *(const bf16x8*)&Vts[cur][nf * 16 + lr][ks * 32 + lg * 8];
                o[nf] = __builtin_amdgcn_mfma_f32_16x16x32_bf16(ap, bv_, o[nf], 0, 0, 0);
            }
        }
        __builtin_amdgcn_s_setprio(0);

        if (pf) {
            *(bf16x8*)&Ks[cur ^ 1][srow][scg]  = kreg;
            *(bf16x8*)&Vts[cur ^ 1][srow][scg] = vreg;
        }
        __syncthreads();
    }

    #pragma unroll
    for (int i = 0; i < 4; i++) {
        #pragma unroll
        for (int xm = 1; xm < 16; xm <<= 1) lsum[i] += __shfl_xor(lsum[i], xm);
    }

    int b = bh >> 4, h = bh & 15;
    #pragma unroll
    for (int i = 0; i < 4; i++) {
        float inv = 1.0f / lsum[i];
        #pragma unroll
        for (int nf = 0; nf < 4; nf++) {
            int m = b * S_ + q0 + w * 16 + lg * 4 + i;
            int d = h * 64 + nf * 16 + lr;
            AO[(size_t)m * D_ + d] = (bf16)(o[nf][i] * inv);
        }
    }
}

// ---------------- launcher ----------------------------------------------------
extern "C" void kernel_launch(void* const* d_in, const int* in_sizes, int n_in,
                              void* d_out, int out_size, void* d_ws, size_t ws_size,
                              hipStream_t stream) {
    const float* xq = (const float*)d_in[0];
    const float* xk = (const float*)d_in[1];
    const float* xv = (const float*)d_in[2];
    const float* wq = (const float*)d_in[4];
    const float* bq = (const float*)d_in[5];
    const float* wk = (const float*)d_in[6];
    const float* bk = (const float*)d_in[7];
    const float* wv = (const float*)d_in[8];
    const float* bv = (const float*)d_in[9];
    const float* wo = (const float*)d_in[10];
    const float* bo = (const float*)d_in[11];
    float* out = (float*)d_out;

    bf16* Xb  = (bf16*)d_ws;                  // region reused for VT
    bf16* Wb  = Xb  + (size_t)3 * M_ * K_;    // [4][N][K]  (q,k,v,o weights ^T)
    bf16* WoT = Wb  + (size_t)3 * N_ * K_;
    bf16* QKV = WoT + (size_t)N_ * K_;        // [3][B*H][S][HD]
    bf16* AO  = QKV + (size_t)3 * M_ * K_;    // [M][D]
    bf16* VT  = Xb;                           // [B*H][HD][S]

    pack_w <<<dim3(N_ * K_ / 256, 4), 256, 0, stream>>>(wq, wk, wv, wo, Wb);
    gemm_qkv<<<dim3(M_ / 128, N_ / 128, 3), 256, 0, stream>>>(xq, xk, xv, Wb, bq, bk, bv, QKV);
    transpose_v<<<dim3(S_ / 64, B_ * H_), 256, 0, stream>>>(QKV + (size_t)2 * M_ * K_, VT);
    attn    <<<dim3(S_ / 128, B_ * H_), 512, 0, stream>>>(QKV, VT, AO);
    gemm_out<<<dim3(M_ / 128, N_ / 128), 256, 0, stream>>>(AO, WoT, bo, out);
}